// Round 8
// baseline (272.858 us; speedup 1.0000x reference)
//
#include <hip/hip_runtime.h>
#include <hip/hip_bf16.h>

#define N_NODES 262144
#define NUM_C   256
#define DIM     128
#define NUM_G   128
#define GMAX    4
#define WPAD    136            // padded LDS row stride (shorts): 272 B, 16B-aligned
#define TILE    64             // nodes per LDS tile
#define NTILE   8              // tiles per block (512 nodes)

typedef short  bf16x8 __attribute__((ext_vector_type(8)));
typedef float  f32x4  __attribute__((ext_vector_type(4)));

__device__ __forceinline__ short f2b(float f) {
    __hip_bfloat16 h = __float2bfloat16(f);
    return *reinterpret_cast<short*>(&h);
}

// Pin a 128-bit value in VGPRs: the asm "modifies" it, so the compiler can
// neither re-materialize the feeding load nor sink it into a loop.
__device__ __forceinline__ void pin4(f32x4& v) {
    asm volatile("" : "+v"(v));
}

// ---------------------------------------------------------------------------
// Prep: zero out, convert W fp32->bf16, compute c_sq, build cum_end[g] from
// the sorted batch. Grid: 128 x 256. (verified r1-r7)
// ---------------------------------------------------------------------------
__global__ void centroid_prep(const float* __restrict__ W,
                              const int* __restrict__ batch,
                              float* __restrict__ out,
                              short* __restrict__ Wb,
                              float* __restrict__ csq,
                              int* __restrict__ cum_end)
{
    const int t   = threadIdx.x;
    const int b   = blockIdx.x;
    const int gid = b * 256 + t;

    float w = W[gid];
    out[gid] = 0.f;
    Wb[gid] = f2b(w);

    __shared__ float red[256];
    red[t] = w * w;
    __syncthreads();
    for (int off = 64; off > 0; off >>= 1) {
        if ((t & 127) < off) red[t] += red[t + off];
        __syncthreads();
    }
    if (t == 0)   csq[2 * b]     = red[0];
    if (t == 128) csq[2 * b + 1] = red[128];

    long i0 = (long)gid * 8;
    int g = batch[i0];
    if (gid == 0) {
        for (int gg = 0; gg < g; ++gg) cum_end[gg] = 0;
    }
    for (int k = 0; k < 8; ++k) {
        long i = i0 + k;
        int gn = (i + 1 < N_NODES) ? batch[i + 1] : NUM_G;
        if (gn != g) {
            for (int gg = g; gg < gn; ++gg) cum_end[gg] = (int)(i + 1);
        }
        g = gn;
    }
}

// ---------------------------------------------------------------------------
// Main (r8, m97-style): 512 blocks x 512 threads (2 blocks/CU, VGPR-bound).
// Block = 512 nodes in 8 tiles of 64. A path: lane-linear coalesced global
// loads -> bf16 cvt -> padded LDS -> ds_read_b128 in MFMA layout (kills the
// 32-line/instr TA divergence of r1-r7). Software pipeline: tile j+2 loads
// issued before compute(j). B-fragments (wave's 64 centroids) pinned in
// VGPRs via asm (r7's compiler re-materialization fix). Fire-and-forget
// LDS atomics for the segment sum (r4+).
// ---------------------------------------------------------------------------
__global__ __launch_bounds__(512, 4) void centroid_main(
    const float* __restrict__ x,
    const int* __restrict__ batch,
    const short* __restrict__ Wb,
    const float* __restrict__ csq,
    float* __restrict__ out)
{
    __shared__ short albuf[2][TILE * WPAD];   // 34816 B
    __shared__ float xsq_l[2][TILE];          //   512 B
    __shared__ float lacc[GMAX * NUM_C];      //  4096 B
    __shared__ int   lbatch[512];             //  2048 B  => ~41.5 KB

    const int t  = threadIdx.x;
    const int nb = blockIdx.x << 9;           // 512 nodes per block

    for (int i = t; i < GMAX * NUM_C; i += 512) lacc[i] = 0.f;
    lbatch[t] = batch[nb + t];

    const int lane = t & 63;
    const int m16  = lane & 15;
    const int quad = lane >> 4;
    const int wv   = t >> 6;                  // 0..7
    const int cq   = wv & 3;                  // c-quarter (64 centroids)
    const int s0   = (wv >> 2) * 2;           // first subtile (0 or 2)

    // ---- B-fragments: 64 VGPR, loaded once, pinned ----
    f32x4 Bp[4][4];
    float cs[4];
#pragma unroll
    for (int ct = 0; ct < 4; ++ct) {
        const int c = cq * 64 + ct * 16 + m16;
        const short* wp = Wb + c * DIM + quad * 8;
#pragma unroll
        for (int ks = 0; ks < 4; ++ks)
            Bp[ct][ks] = *(const f32x4*)(wp + ks * 32);
        cs[ct] = csq[c];
    }
#pragma unroll
    for (int ct = 0; ct < 4; ++ct)
#pragma unroll
        for (int ks = 0; ks < 4; ++ks)
            pin4(Bp[ct][ks]);

    // ---- staging roles: thread = (row, 64B segment) ----
    const int srow = t >> 3;                  // 0..63
    const int sseg = t & 7;                   // 0..7 (16 floats each)

    f32x4 u[4];                               // in-flight x registers

#define ISSUE_LOADS(J)                                                     \
    {                                                                      \
        const float* p = x + (size_t)(nb + (J) * TILE + srow) * DIM        \
                           + sseg * 16;                                    \
        u[0] = *(const f32x4*)(p);                                         \
        u[1] = *(const f32x4*)(p + 4);                                     \
        u[2] = *(const f32x4*)(p + 8);                                     \
        u[3] = *(const f32x4*)(p + 12);                                    \
    }

#define STAGE(J)                                                           \
    {                                                                      \
        const int buf = (J) & 1;                                           \
        float ss = 0.f;                                                    \
        bf16x8 h0, h1;                                                     \
        _Pragma("unroll")                                                  \
        for (int i = 0; i < 2; ++i) {                                      \
            f32x4 v = u[i];                                                \
            _Pragma("unroll")                                              \
            for (int k = 0; k < 4; ++k) {                                  \
                ss += v[k] * v[k];                                         \
                h0[i * 4 + k] = f2b(v[k]);                                 \
            }                                                              \
        }                                                                  \
        _Pragma("unroll")                                                  \
        for (int i = 0; i < 2; ++i) {                                      \
            f32x4 v = u[i + 2];                                            \
            _Pragma("unroll")                                              \
            for (int k = 0; k < 4; ++k) {                                  \
                ss += v[k] * v[k];                                         \
                h1[i * 4 + k] = f2b(v[k]);                                 \
            }                                                              \
        }                                                                  \
        ss += __shfl_xor(ss, 1);                                           \
        ss += __shfl_xor(ss, 2);                                           \
        ss += __shfl_xor(ss, 4);                                           \
        short* dst = albuf[buf] + srow * WPAD + sseg * 16;                 \
        *(bf16x8*)dst       = h0;                                          \
        *(bf16x8*)(dst + 8) = h1;                                          \
        if (sseg == 0) xsq_l[buf][srow] = ss;                              \
    }

    // ---- prologue ----
    ISSUE_LOADS(0);
    STAGE(0);
    ISSUE_LOADS(1);
    __syncthreads();                          // buf0 + lacc/lbatch visible

    const int  gmin    = lbatch[0];
    const int  span    = lbatch[511] - gmin + 1;
    const bool use_lds = (span <= GMAX);

    // ---- tile loop ----
#pragma unroll 1
    for (int j = 0; j < NTILE; ++j) {
        if (j + 1 < NTILE) STAGE(j + 1);      // consume u -> buf (j+1)&1
        if (j + 2 < NTILE) ISSUE_LOADS(j + 2);// refill u; covered by compute

        const short* ab = albuf[j & 1];
        const float* xq = xsq_l[j & 1];

#pragma unroll
        for (int si = 0; si < 2; ++si) {
            const int s = s0 + si;
            const short* ap = ab + (s * 16 + m16) * WPAD + quad * 8;
            bf16x8 a0 = *(const bf16x8*)(ap);
            bf16x8 a1 = *(const bf16x8*)(ap + 32);
            bf16x8 a2 = *(const bf16x8*)(ap + 64);
            bf16x8 a3 = *(const bf16x8*)(ap + 96);
            float pre[4];
#pragma unroll
            for (int r = 0; r < 4; ++r) pre[r] = xq[s * 16 + quad * 4 + r];

            const int  l0  = j * TILE + s * 16;
            const int  g0  = lbatch[l0];
            const bool uni = (g0 == lbatch[l0 + 15]);
            float* lrow = &lacc[(g0 - gmin) * NUM_C];

#pragma unroll
            for (int ct = 0; ct < 4; ++ct) {
                f32x4 acc = {0.f, 0.f, 0.f, 0.f};
                acc = __builtin_amdgcn_mfma_f32_16x16x32_bf16(
                          a0, __builtin_bit_cast(bf16x8, Bp[ct][0]), acc, 0, 0, 0);
                acc = __builtin_amdgcn_mfma_f32_16x16x32_bf16(
                          a1, __builtin_bit_cast(bf16x8, Bp[ct][1]), acc, 0, 0, 0);
                acc = __builtin_amdgcn_mfma_f32_16x16x32_bf16(
                          a2, __builtin_bit_cast(bf16x8, Bp[ct][2]), acc, 0, 0, 0);
                acc = __builtin_amdgcn_mfma_f32_16x16x32_bf16(
                          a3, __builtin_bit_cast(bf16x8, Bp[ct][3]), acc, 0, 0, 0);

                const int c = cq * 64 + ct * 16 + m16;
                if (use_lds && uni) {
                    float v = 0.f;
#pragma unroll
                    for (int r = 0; r < 4; ++r) {
                        float d2 = __builtin_fmaf(acc[r], -2.f, pre[r] + cs[ct]);
                        v += __builtin_amdgcn_sqrtf(__builtin_fmaxf(d2, 0.f));
                    }
                    atomicAdd(&lrow[c], v);   // fire-and-forget
                } else {
#pragma unroll
                    for (int r = 0; r < 4; ++r) {
                        float d2 = __builtin_fmaf(acc[r], -2.f, pre[r] + cs[ct]);
                        float d  = __builtin_amdgcn_sqrtf(__builtin_fmaxf(d2, 0.f));
                        int   g  = lbatch[l0 + quad * 4 + r];
                        if (use_lds) atomicAdd(&lacc[(g - gmin) * NUM_C + c], d);
                        else         atomicAdd(&out[g * NUM_C + c], d);
                    }
                }
            }
        }

        __syncthreads();   // staged tile j+1 visible; j+2 loads had cover
    }

    if (use_lds) {
        for (int i = t; i < span * NUM_C; i += 512)
            atomicAdd(&out[(gmin + (i >> 8)) * NUM_C + (i & 255)], lacc[i]);
    }
#undef ISSUE_LOADS
#undef STAGE
}

// ---------------------------------------------------------------------------
// Finish: divide sums by per-graph counts. Grid: 128 x 256.
// ---------------------------------------------------------------------------
__global__ void centroid_finish(float* __restrict__ out,
                                const int* __restrict__ cum_end)
{
    const int g = blockIdx.x;
    const int c = threadIdx.x;
    int cnt = cum_end[g] - (g ? cum_end[g - 1] : 0);
    float denom = (float)(cnt > 0 ? cnt : 1);
    out[g * NUM_C + c] /= denom;
}

extern "C" void kernel_launch(void* const* d_in, const int* in_sizes, int n_in,
                              void* d_out, int out_size, void* d_ws, size_t ws_size,
                              hipStream_t stream) {
    const float* x     = (const float*)d_in[0];
    const int*   batch = (const int*)d_in[1];
    const float* W     = (const float*)d_in[2];
    float*       out   = (float*)d_out;

    // workspace: Wb (64 KB) | csq (1 KB) | cum_end (512 B)
    short* Wb      = (short*)d_ws;
    float* csq     = (float*)((char*)d_ws + 65536);
    int*   cum_end = (int*)((char*)d_ws + 65536 + 1024);

    centroid_prep<<<128, 256, 0, stream>>>(W, batch, out, Wb, csq, cum_end);
    centroid_main<<<N_NODES / 512, 512, 0, stream>>>(x, batch, Wb, csq, out);
    centroid_finish<<<NUM_G, 256, 0, stream>>>(out, cum_end);
}